// Round 3
// baseline (485.645 us; speedup 1.0000x reference)
//
#include <hip/hip_runtime.h>
#include <hip/hip_bf16.h>
#include <stdint.h>

#define DIM_ 1024
#define NH_ 16
#define HD_ 64
#define B_ 4
#define S_ 2048
#define SC_ 1024
#define CD_ 768

typedef __attribute__((ext_vector_type(8))) short bf16x8;
typedef __attribute__((ext_vector_type(4))) short bf16x4;
typedef __attribute__((ext_vector_type(4))) float f32x4;

__device__ inline unsigned short f2bf(float f) {
    unsigned int u = __builtin_bit_cast(unsigned int, f);
    unsigned int r = (u + 0x7FFFu + ((u >> 16) & 1u)) >> 16;
    return (unsigned short)r;
}

// ---------------- conversion kernels ----------------
__global__ void k_f32_to_bf16(const float* __restrict__ in, unsigned short* __restrict__ out, int n4) {
    int i = blockIdx.x * blockDim.x + threadIdx.x;
    int stride = gridDim.x * blockDim.x;
    for (; i < n4; i += stride) {
        float4 v = ((const float4*)in)[i];
        uint2 pk;
        pk.x = (unsigned int)f2bf(v.x) | ((unsigned int)f2bf(v.y) << 16);
        pk.y = (unsigned int)f2bf(v.z) | ((unsigned int)f2bf(v.w) << 16);
        ((uint2*)out)[i] = pk;
    }
}

// W is (K x 1024), write WT (1024 x K) in bf16
__global__ void k_transposeW(const float* __restrict__ W, unsigned short* __restrict__ WT, int K) {
    int idx = blockIdx.x * blockDim.x + threadIdx.x;
    int total = K * 1024;
    int stride = gridDim.x * blockDim.x;
    for (; idx < total; idx += stride) {
        int k = idx >> 10, n = idx & 1023;
        WT[n * K + k] = f2bf(W[idx]);
    }
}

// Build per-batch key-padding bitmask (bit=1 -> masked). Handles both byte-bool
// and int32 uploads of the mask: probe first 4096 bytes (= whole mask in byte
// mode, = batch 0 in int mode); any 32-bit word >1 can only occur byte-packed.
__global__ void k_mask_bits(const unsigned int* __restrict__ m, unsigned int* __restrict__ bits) {
    __shared__ int bm_s;
    if (threadIdx.x == 0) bm_s = 0;
    __syncthreads();
    int any = 0;
    for (int i = threadIdx.x; i < 1024; i += 256)
        if (m[i] > 1u) any = 1;
    if (any) atomicOr(&bm_s, 1);
    __syncthreads();
    const int boolmode = bm_s;
    const int w = threadIdx.x;
    if (w < 128) {  // 4 batches * 32 words
        const unsigned char* mb = (const unsigned char*)m;
        unsigned int out = 0;
        for (int j = 0; j < 32; ++j) {
            int c = w * 32 + j;
            int masked = boolmode ? (mb[c] != 0) : (m[c] != 0u);
            out |= (unsigned int)masked << j;
        }
        bits[w] = out;
    }
}

// ---------------- bf16 GEMM, B^T layout, global_load_lds staging (m97 pattern) ----------------
template<int EPI>
__global__ __launch_bounds__(256) void k_gemm_bt(
    const unsigned short* __restrict__ A, const unsigned short* __restrict__ BT,
    const float* __restrict__ bias, unsigned short* __restrict__ Cb, float* __restrict__ Cf,
    int M, int N, int K)
{
    __shared__ unsigned short As[128 * 32];
    __shared__ unsigned short Bs[128 * 32];
    const int t = threadIdx.x;
    const int w = t >> 6, lane = t & 63;
    const int lo = lane & 15, hi = lane >> 4;
    const int m0 = blockIdx.x * 128, n0 = blockIdx.y * 128;
    const int wr = (w >> 1) * 64, wc = (w & 1) * 64;
    const int srow = lane >> 2;
    const int scol = (lane & 3) * 8;

    f32x4 zero4 = {0.f, 0.f, 0.f, 0.f};
    f32x4 acc[4][4];
    for (int i = 0; i < 4; ++i)
        for (int j = 0; j < 4; ++j) acc[i][j] = zero4;

    for (int k0 = 0; k0 < K; k0 += 32) {
#pragma unroll
        for (int p = 0; p < 2; ++p) {
            int chunk = w * 2 + p;
            int r = chunk * 16 + srow;
            __builtin_amdgcn_global_load_lds(
                (const __attribute__((address_space(1))) void*)&A[(size_t)(m0 + r) * K + k0 + scol],
                (__attribute__((address_space(3))) void*)&As[chunk * 512], 16, 0, 0);
            __builtin_amdgcn_global_load_lds(
                (const __attribute__((address_space(1))) void*)&BT[(size_t)(n0 + r) * K + k0 + scol],
                (__attribute__((address_space(3))) void*)&Bs[chunk * 512], 16, 0, 0);
        }
        __syncthreads();
        bf16x8 af[4], bfr[4];
#pragma unroll
        for (int i = 0; i < 4; ++i)
            af[i] = *(const bf16x8*)&As[(wr + i * 16 + lo) * 32 + (hi << 3)];
#pragma unroll
        for (int j = 0; j < 4; ++j)
            bfr[j] = *(const bf16x8*)&Bs[(wc + j * 16 + lo) * 32 + (hi << 3)];
#pragma unroll
        for (int i = 0; i < 4; ++i)
#pragma unroll
            for (int j = 0; j < 4; ++j)
                acc[i][j] = __builtin_amdgcn_mfma_f32_16x16x32_bf16(af[i], bfr[j], acc[i][j], 0, 0, 0);
        __syncthreads();
    }

#pragma unroll
    for (int i = 0; i < 4; ++i) {
#pragma unroll
        for (int j = 0; j < 4; ++j) {
#pragma unroll
            for (int r = 0; r < 4; ++r) {
                int m = m0 + wr + i * 16 + (hi << 2) + r;
                int n = n0 + wc + j * 16 + lo;
                float v = acc[i][j][r] + bias[n];
                if (EPI == 0) {
                    Cb[(size_t)m * N + n] = f2bf(v);
                } else if (EPI == 1) {
                    int b = m >> 10, c = m & 1023;
                    Cb[(size_t)((b << 10) + n) * 1024 + c] = f2bf(v);
                } else {
                    Cf[(size_t)m * N + n] = v;
                }
            }
        }
    }
}

// ---------------- fused flash attention: swapped-QK^T, in-register softmax ----------------
// grid (S/64, NH, B), 256 threads, 4 waves x 16 q-rows. KV tile = 64. No LDS in loop.
// S^T = mfma(K_frag, Q_frag): lane holds S^T[kv = n*16+hi*4+r][q = lane&15] -> softmax
// row (over kv) is lane-local (16 vals) + shfl_xor(16,32). P^T chunks feed
// v_mfma_f32_16x16x16_bf16 (K=16) directly as B; A = V^T rows; O^T accumulates in regs.
__global__ __launch_bounds__(256) void k_attn(
    const unsigned short* __restrict__ Q, const unsigned short* __restrict__ Kb,
    const unsigned short* __restrict__ VT, const unsigned int* __restrict__ bits,
    unsigned short* __restrict__ Ob)
{
    __shared__ unsigned short T[4][16][72];  // epilogue transpose only; wave-private
    const int t = threadIdx.x, w = t >> 6, lane = t & 63;
    const int lo = lane & 15, hi = lane >> 4;
    const int qt = blockIdx.x, h = blockIdx.y, b = blockIdx.z;
    const int qr0 = qt * 64 + w * 16;

    bf16x8 qf[2];
#pragma unroll
    for (int kk = 0; kk < 2; ++kk)
        qf[kk] = *(const bf16x8*)&Q[(size_t)(b * S_ + qr0 + lo) * DIM_ + h * 64 + kk * 32 + hi * 8];

    f32x4 zero4 = {0.f, 0.f, 0.f, 0.f};
    float mrow = -1e30f, lsum = 0.f;   // per-lane scalars: this lane's q-row = lo
    f32x4 o[4];                         // O^T[d = dt*16+hi*4+r][q = lo]
#pragma unroll
    for (int dt = 0; dt < 4; ++dt) o[dt] = zero4;

    for (int c0 = 0; c0 < SC_; c0 += 64) {
        // K fragments (A-operand): lane holds K[c0+n*16+lo][kk*32+hi*8 ..+7]
        bf16x8 kf[4][2];
#pragma unroll
        for (int n = 0; n < 4; ++n)
#pragma unroll
            for (int kk = 0; kk < 2; ++kk)
                kf[n][kk] = *(const bf16x8*)&Kb[(size_t)(b * SC_ + c0 + n * 16 + lo) * DIM_ + h * 64 + kk * 32 + hi * 8];
        // V^T fragments for K=16 PV (A-operand): lane holds V^T[dt*16+lo][c0+n*16+hi*4 ..+3]
        bf16x4 vf[4][4];
#pragma unroll
        for (int dt = 0; dt < 4; ++dt)
#pragma unroll
            for (int n = 0; n < 4; ++n)
                vf[dt][n] = *(const bf16x4*)&VT[(size_t)(b * DIM_ + h * 64 + dt * 16 + lo) * SC_ + c0 + n * 16 + hi * 4];
        uint2 mw = *(const uint2*)&bits[b * 32 + (c0 >> 5)];

        // S^T tiles: rows kv (n*16+hi*4+r), cols q (lo)
        f32x4 st[4];
#pragma unroll
        for (int n = 0; n < 4; ++n) st[n] = zero4;
#pragma unroll
        for (int n = 0; n < 4; ++n) {
            st[n] = __builtin_amdgcn_mfma_f32_16x16x32_bf16(kf[n][0], qf[0], st[n], 0, 0, 0);
            st[n] = __builtin_amdgcn_mfma_f32_16x16x32_bf16(kf[n][1], qf[1], st[n], 0, 0, 0);
        }

        // scale + mask (bit test) + lane-local max
        float p[4][4];
        float mx = -1e30f;
#pragma unroll
        for (int n = 0; n < 4; ++n) {
            unsigned int wd = (n & 2) ? mw.y : mw.x;
#pragma unroll
            for (int r = 0; r < 4; ++r) {
                int sh = (n & 1) * 16 + hi * 4 + r;
                float s = ((wd >> sh) & 1u) ? -1e30f : st[n][r] * 0.125f;
                p[n][r] = s;
                mx = fmaxf(mx, s);
            }
        }
        mx = fmaxf(mx, __shfl_xor(mx, 16));
        mx = fmaxf(mx, __shfl_xor(mx, 32));
        float mnew = fmaxf(mrow, mx);
        float scl = __expf(mrow - mnew);
        mrow = mnew;

        float rs = 0.f;
#pragma unroll
        for (int n = 0; n < 4; ++n)
#pragma unroll
            for (int r = 0; r < 4; ++r) {
                float e = __expf(p[n][r] - mnew);
                p[n][r] = e;
                rs += e;
            }
        rs += __shfl_xor(rs, 16);
        rs += __shfl_xor(rs, 32);
        lsum = lsum * scl + rs;

#pragma unroll
        for (int dt = 0; dt < 4; ++dt)
#pragma unroll
            for (int r = 0; r < 4; ++r)
                o[dt][r] *= scl;

        // pack P^T chunks to bf16x4 (B-operand of K=16 mfma)
        bf16x4 pb[4];
#pragma unroll
        for (int n = 0; n < 4; ++n) {
            uint2 pk;
            pk.x = (unsigned int)f2bf(p[n][0]) | ((unsigned int)f2bf(p[n][1]) << 16);
            pk.y = (unsigned int)f2bf(p[n][2]) | ((unsigned int)f2bf(p[n][3]) << 16);
            pb[n] = __builtin_bit_cast(bf16x4, pk);
        }
        // PV: O^T[d][q] += sum_kv V^T[d][kv] * P^T[kv][q]
#pragma unroll
        for (int dt = 0; dt < 4; ++dt)
#pragma unroll
            for (int n = 0; n < 4; ++n)
                o[dt] = __builtin_amdgcn_mfma_f32_16x16x16bf16_1k(vf[dt][n], pb[n], o[dt], 0, 0, 0);
    }

    // epilogue: O^T -> O via wave-private LDS transpose, then coalesced 16B stores
    float inv = 1.0f / lsum;
#pragma unroll
    for (int dt = 0; dt < 4; ++dt)
#pragma unroll
        for (int r = 0; r < 4; ++r)
            T[w][lo][dt * 16 + hi * 4 + r] = f2bf(o[dt][r] * inv);
    // same-wave ds_write -> ds_read: compiler inserts lgkmcnt wait
#pragma unroll
    for (int ps = 0; ps < 2; ++ps) {
        int row = ps * 8 + (lane >> 3);
        int col = (lane & 7) * 8;
        bf16x8 v = *(const bf16x8*)&T[w][row][col];
        *(bf16x8*)&Ob[(size_t)(b * S_ + qr0 + row) * DIM_ + h * 64 + col] = v;
    }
}

// ---------------- launch ----------------
extern "C" void kernel_launch(void* const* d_in, const int* in_sizes, int n_in,
                              void* d_out, int out_size, void* d_ws, size_t ws_size,
                              hipStream_t stream)
{
    const float* x  = (const float*)d_in[0];
    const float* cx = (const float*)d_in[1];
    const void* mask = d_in[2];
    const float* Wq = (const float*)d_in[3];
    const float* bq = (const float*)d_in[4];
    const float* Wk = (const float*)d_in[5];
    const float* bk = (const float*)d_in[6];
    const float* Wv = (const float*)d_in[7];
    const float* bv = (const float*)d_in[8];
    const float* Wo = (const float*)d_in[9];
    const float* bo = (const float*)d_in[10];

    unsigned short* ws = (unsigned short*)d_ws;
    const size_t XB  = 0;                                  // 8192*1024 (x bf16; later attn out)
    const size_t CXB = XB  + (size_t)8192 * 1024;          // 4096*768
    const size_t WQT = CXB + (size_t)4096 * 768;           // 1024*1024
    const size_t WKT = WQT + (size_t)1024 * 1024;          // 1024*768
    const size_t WVT = WKT + (size_t)1024 * 768;           // 1024*768
    const size_t WOT = WVT + (size_t)1024 * 768;           // 1024*1024
    const size_t QB  = WOT + (size_t)1024 * 1024;          // 8192*1024
    const size_t KB  = QB  + (size_t)8192 * 1024;          // 4096*1024
    const size_t VTB = KB  + (size_t)4096 * 1024;          // 4*1024*1024
    const size_t MBT = VTB + (size_t)4 * 1024 * 1024;      // 128 uint32 = 256 ushort

    k_f32_to_bf16<<<2048, 256, 0, stream>>>(x,  ws + XB,  8192 * 1024 / 4);
    k_f32_to_bf16<<<2048, 256, 0, stream>>>(cx, ws + CXB, 4096 * 768 / 4);
    k_transposeW<<<1024, 256, 0, stream>>>(Wq, ws + WQT, 1024);
    k_transposeW<<<768,  256, 0, stream>>>(Wk, ws + WKT, 768);
    k_transposeW<<<768,  256, 0, stream>>>(Wv, ws + WVT, 768);
    k_transposeW<<<1024, 256, 0, stream>>>(Wo, ws + WOT, 1024);
    unsigned int* mbits = (unsigned int*)(ws + MBT);
    k_mask_bits<<<1, 256, 0, stream>>>((const unsigned int*)mask, mbits);

    dim3 gq(8192 / 128, 1024 / 128);
    dim3 gk(4096 / 128, 1024 / 128);
    k_gemm_bt<0><<<gq, 256, 0, stream>>>(ws + XB,  ws + WQT, bq, ws + QB, nullptr, 8192, 1024, 1024);
    k_gemm_bt<0><<<gk, 256, 0, stream>>>(ws + CXB, ws + WKT, bk, ws + KB, nullptr, 4096, 1024, 768);
    k_gemm_bt<1><<<gk, 256, 0, stream>>>(ws + CXB, ws + WVT, bv, ws + VTB, nullptr, 4096, 1024, 768);

    dim3 ga(S_ / 64, NH_, B_);
    k_attn<<<ga, 256, 0, stream>>>(ws + QB, ws + KB, ws + VTB, mbits, ws + XB);

    k_gemm_bt<2><<<gq, 256, 0, stream>>>(ws + XB, ws + WOT, bo, nullptr, (float*)d_out, 8192, 1024, 1024);
}

// Round 4
// 227.201 us; speedup vs baseline: 2.1375x; 2.1375x over previous
//
#include <hip/hip_runtime.h>
#include <hip/hip_bf16.h>
#include <stdint.h>

#define DIM_ 1024
#define NH_ 16
#define HD_ 64
#define B_ 4
#define S_ 2048
#define SC_ 1024
#define CD_ 768

typedef __attribute__((ext_vector_type(8))) short bf16x8;
typedef __attribute__((ext_vector_type(4))) short bf16x4;
typedef __attribute__((ext_vector_type(4))) float f32x4;

__device__ inline unsigned short f2bf(float f) {
    unsigned int u = __builtin_bit_cast(unsigned int, f);
    unsigned int r = (u + 0x7FFFu + ((u >> 16) & 1u)) >> 16;
    return (unsigned short)r;
}

#define GLOAD16(SRC, DST) __builtin_amdgcn_global_load_lds( \
    (const __attribute__((address_space(1))) void*)(SRC),   \
    (__attribute__((address_space(3))) void*)(DST), 16, 0, 0)

// ---------------- conversion kernels ----------------
__global__ void k_f32_to_bf16(const float* __restrict__ in, unsigned short* __restrict__ out, int n4) {
    int i = blockIdx.x * blockDim.x + threadIdx.x;
    int stride = gridDim.x * blockDim.x;
    for (; i < n4; i += stride) {
        float4 v = ((const float4*)in)[i];
        uint2 pk;
        pk.x = (unsigned int)f2bf(v.x) | ((unsigned int)f2bf(v.y) << 16);
        pk.y = (unsigned int)f2bf(v.z) | ((unsigned int)f2bf(v.w) << 16);
        ((uint2*)out)[i] = pk;
    }
}

__global__ void k_transposeW(const float* __restrict__ W, unsigned short* __restrict__ WT, int K) {
    int idx = blockIdx.x * blockDim.x + threadIdx.x;
    int total = K * 1024;
    int stride = gridDim.x * blockDim.x;
    for (; idx < total; idx += stride) {
        int k = idx >> 10, n = idx & 1023;
        WT[n * K + k] = f2bf(W[idx]);
    }
}

// per-batch key-padding bitmask (bit=1 -> masked); handles byte-bool or int32 upload
__global__ void k_mask_bits(const unsigned int* __restrict__ m, unsigned int* __restrict__ bits) {
    __shared__ int bm_s;
    if (threadIdx.x == 0) bm_s = 0;
    __syncthreads();
    int any = 0;
    for (int i = threadIdx.x; i < 1024; i += 256)
        if (m[i] > 1u) any = 1;
    if (any) atomicOr(&bm_s, 1);
    __syncthreads();
    const int boolmode = bm_s;
    const int w = threadIdx.x;
    if (w < 128) {
        const unsigned char* mb = (const unsigned char*)m;
        unsigned int out = 0;
        for (int j = 0; j < 32; ++j) {
            int c = w * 32 + j;
            int masked = boolmode ? (mb[c] != 0) : (m[c] != 0u);
            out |= (unsigned int)masked << j;
        }
        bits[w] = out;
    }
}

// ---------------- bf16 GEMM, B^T layout, global_load_lds staging (m97 pattern) ----------------
template<int EPI>
__global__ __launch_bounds__(256) void k_gemm_bt(
    const unsigned short* __restrict__ A, const unsigned short* __restrict__ BT,
    const float* __restrict__ bias, unsigned short* __restrict__ Cb, float* __restrict__ Cf,
    int M, int N, int K)
{
    __shared__ unsigned short As[128 * 32];
    __shared__ unsigned short Bs[128 * 32];
    const int t = threadIdx.x;
    const int w = t >> 6, lane = t & 63;
    const int lo = lane & 15, hi = lane >> 4;
    const int m0 = blockIdx.x * 128, n0 = blockIdx.y * 128;
    const int wr = (w >> 1) * 64, wc = (w & 1) * 64;
    const int srow = lane >> 2;
    const int scol = (lane & 3) * 8;

    f32x4 zero4 = {0.f, 0.f, 0.f, 0.f};
    f32x4 acc[4][4];
    for (int i = 0; i < 4; ++i)
        for (int j = 0; j < 4; ++j) acc[i][j] = zero4;

    for (int k0 = 0; k0 < K; k0 += 32) {
#pragma unroll
        for (int p = 0; p < 2; ++p) {
            int chunk = w * 2 + p;
            int r = chunk * 16 + srow;
            GLOAD16(&A[(size_t)(m0 + r) * K + k0 + scol], &As[chunk * 512]);
            GLOAD16(&BT[(size_t)(n0 + r) * K + k0 + scol], &Bs[chunk * 512]);
        }
        __syncthreads();
        bf16x8 af[4], bfr[4];
#pragma unroll
        for (int i = 0; i < 4; ++i)
            af[i] = *(const bf16x8*)&As[(wr + i * 16 + lo) * 32 + (hi << 3)];
#pragma unroll
        for (int j = 0; j < 4; ++j)
            bfr[j] = *(const bf16x8*)&Bs[(wc + j * 16 + lo) * 32 + (hi << 3)];
#pragma unroll
        for (int i = 0; i < 4; ++i)
#pragma unroll
            for (int j = 0; j < 4; ++j)
                acc[i][j] = __builtin_amdgcn_mfma_f32_16x16x32_bf16(af[i], bfr[j], acc[i][j], 0, 0, 0);
        __syncthreads();
    }

#pragma unroll
    for (int i = 0; i < 4; ++i) {
#pragma unroll
        for (int j = 0; j < 4; ++j) {
#pragma unroll
            for (int r = 0; r < 4; ++r) {
                int m = m0 + wr + i * 16 + (hi << 2) + r;
                int n = n0 + wc + j * 16 + lo;
                float v = acc[i][j][r] + bias[n];
                if (EPI == 0) {
                    Cb[(size_t)m * N + n] = f2bf(v);
                } else if (EPI == 1) {
                    int b = m >> 10, c = m & 1023;
                    Cb[(size_t)((b << 10) + n) * 1024 + c] = f2bf(v);
                } else {
                    Cf[(size_t)m * N + n] = v;
                }
            }
        }
    }
}

// ---------------- fused flash attention: LDS-staged K/V, swapped-QK^T, in-reg softmax ----------------
// grid (S/128, NH, B), 256 threads = 4 waves x 32 q-rows. KV tile 64, double-buffered LDS.
// K,V tiles staged once per block via global_load_lds (coalesced 128B rows) with XOR
// block-swizzle: LDS block index = c ^ (row&7), achieved by pre-swizzling the GLOBAL
// source per lane (rule: both-sides-or-neither). ds_reads apply the same XOR.
__global__ __launch_bounds__(256) void k_attn(
    const unsigned short* __restrict__ Q, const unsigned short* __restrict__ Kb,
    const unsigned short* __restrict__ VT, const unsigned int* __restrict__ bits,
    unsigned short* __restrict__ Ob)
{
    __shared__ unsigned short lds[16384];  // K0|K1|V0|V1, 4096 ushorts (64x64) each
    const int t = threadIdx.x, w = t >> 6, lane = t & 63;
    const int lo = lane & 15, hi = lane >> 4;
    const int qt = blockIdx.x, h = blockIdx.y, b = blockIdx.z;
    const int qr0 = qt * 128 + w * 32;
    const int l7 = lo & 7;

    // staging source column-block (pre-swizzled): block (lane&7) ^ (lane>>3)
    const int srow = lane >> 3;                 // 0..7 within 8-row sub-pass
    const int scb  = ((lane & 7) ^ srow) << 3;  // element offset of fetched 16B block

    bf16x8 qf[2][2];
#pragma unroll
    for (int qh = 0; qh < 2; ++qh)
#pragma unroll
        for (int kk = 0; kk < 2; ++kk)
            qf[qh][kk] = *(const bf16x8*)&Q[(size_t)(b * S_ + qr0 + qh * 16 + lo) * DIM_ + h * 64 + kk * 32 + hi * 8];

    f32x4 zero4 = {0.f, 0.f, 0.f, 0.f};
    float mrow[2] = {-1e30f, -1e30f}, lsum[2] = {0.f, 0.f};
    f32x4 o[4][2];
#pragma unroll
    for (int dt = 0; dt < 4; ++dt)
#pragma unroll
        for (int qh = 0; qh < 2; ++qh) o[dt][qh] = zero4;

    // prologue: stage tile 0 into buf 0
#pragma unroll
    for (int s = 0; s < 2; ++s) {
        int rl = w * 16 + s * 8 + srow;
        GLOAD16(&Kb[(size_t)(b * SC_ + rl) * DIM_ + h * 64 + scb], &lds[(w * 16 + s * 8) * 64]);
        GLOAD16(&VT[(size_t)(b * 1024 + h * 64 + rl) * SC_ + scb], &lds[8192 + (w * 16 + s * 8) * 64]);
    }
    __syncthreads();

    int cur = 0;
    for (int tt = 0; tt < 16; ++tt) {
        if (tt < 15) {  // stage next tile into other buffer (drains at this iter's barrier)
            int c0n = (tt + 1) * 64;
#pragma unroll
            for (int s = 0; s < 2; ++s) {
                int rl = w * 16 + s * 8 + srow;
                GLOAD16(&Kb[(size_t)(b * SC_ + c0n + rl) * DIM_ + h * 64 + scb],
                        &lds[(cur ^ 1) * 4096 + (w * 16 + s * 8) * 64]);
                GLOAD16(&VT[(size_t)(b * 1024 + h * 64 + rl) * SC_ + c0n + scb],
                        &lds[8192 + (cur ^ 1) * 4096 + (w * 16 + s * 8) * 64]);
            }
        }
        const unsigned short* Kl = &lds[cur * 4096];
        const unsigned short* Vl = &lds[8192 + cur * 4096];

        // QK^T (swapped): st[n][qh] rows kv = n*16+hi*4+r, cols q = lo (of half qh)
        f32x4 st[4][2];
#pragma unroll
        for (int n = 0; n < 4; ++n) {
#pragma unroll
            for (int qh = 0; qh < 2; ++qh) st[n][qh] = zero4;
        }
#pragma unroll
        for (int n = 0; n < 4; ++n) {
            const int R = n * 16 + lo;
            bf16x8 k0 = *(const bf16x8*)&Kl[R * 64 + ((hi ^ l7) << 3)];
            bf16x8 k1 = *(const bf16x8*)&Kl[R * 64 + (((4 + hi) ^ l7) << 3)];
#pragma unroll
            for (int qh = 0; qh < 2; ++qh) {
                st[n][qh] = __builtin_amdgcn_mfma_f32_16x16x32_bf16(k0, qf[qh][0], st[n][qh], 0, 0, 0);
                st[n][qh] = __builtin_amdgcn_mfma_f32_16x16x32_bf16(k1, qf[qh][1], st[n][qh], 0, 0, 0);
            }
        }
        // V^T fragments for K=16 PV (A-operand): V^T[dt*16+lo][n*16+hi*4 ..+3]
        bf16x4 vf[4][4];
#pragma unroll
        for (int dt = 0; dt < 4; ++dt)
#pragma unroll
            for (int n = 0; n < 4; ++n)
                vf[dt][n] = *(const bf16x4*)&Vl[(dt * 16 + lo) * 64
                              + (((2 * n + (hi >> 1)) ^ l7) << 3) + ((hi & 1) << 2)];

        uint2 mw = *(const uint2*)&bits[b * 32 + tt * 2];

        float p[2][4][4];
        float mx[2] = {-1e30f, -1e30f};
#pragma unroll
        for (int n = 0; n < 4; ++n) {
            unsigned int wd = (n & 2) ? mw.y : mw.x;
#pragma unroll
            for (int r = 0; r < 4; ++r) {
                int sh = ((n & 1) << 4) + (hi << 2) + r;
                bool mk = (wd >> sh) & 1u;
#pragma unroll
                for (int qh = 0; qh < 2; ++qh) {
                    float s = mk ? -1e30f : st[n][qh][r] * 0.125f;
                    p[qh][n][r] = s;
                    mx[qh] = fmaxf(mx[qh], s);
                }
            }
        }
#pragma unroll
        for (int qh = 0; qh < 2; ++qh) {
            float m2 = fmaxf(mx[qh], __shfl_xor(mx[qh], 16));
            m2 = fmaxf(m2, __shfl_xor(m2, 32));
            float mnew = fmaxf(mrow[qh], m2);
            float scl = __expf(mrow[qh] - mnew);
            mrow[qh] = mnew;
            float rs = 0.f;
#pragma unroll
            for (int n = 0; n < 4; ++n)
#pragma unroll
                for (int r = 0; r < 4; ++r) {
                    float e = __expf(p[qh][n][r] - mnew);
                    p[qh][n][r] = e;
                    rs += e;
                }
            rs += __shfl_xor(rs, 16);
            rs += __shfl_xor(rs, 32);
            lsum[qh] = lsum[qh] * scl + rs;
#pragma unroll
            for (int dt = 0; dt < 4; ++dt)
#pragma unroll
                for (int r = 0; r < 4; ++r)
                    o[dt][qh][r] *= scl;
        }
        // pack P^T and PV (K=16): O^T[d][q] += V^T[d][kv] * P^T[kv][q]
#pragma unroll
        for (int qh = 0; qh < 2; ++qh) {
#pragma unroll
            for (int n = 0; n < 4; ++n) {
                uint2 pk;
                pk.x = (unsigned int)f2bf(p[qh][n][0]) | ((unsigned int)f2bf(p[qh][n][1]) << 16);
                pk.y = (unsigned int)f2bf(p[qh][n][2]) | ((unsigned int)f2bf(p[qh][n][3]) << 16);
                bf16x4 pb = __builtin_bit_cast(bf16x4, pk);
#pragma unroll
                for (int dt = 0; dt < 4; ++dt)
                    o[dt][qh] = __builtin_amdgcn_mfma_f32_16x16x16bf16_1k(vf[dt][n], pb, o[dt][qh], 0, 0, 0);
            }
        }
        __syncthreads();  // drains stage vmcnt + all waves' LDS reads of buf[cur]
        cur ^= 1;
    }

    // epilogue: O^T -> O via wave-private LDS transpose (reuses stage buffers post-barrier)
    unsigned short* Tl = &lds[w * 2304];  // [32][72]
    float inv[2] = {1.0f / lsum[0], 1.0f / lsum[1]};
#pragma unroll
    for (int qh = 0; qh < 2; ++qh)
#pragma unroll
        for (int dt = 0; dt < 4; ++dt)
#pragma unroll
            for (int r = 0; r < 4; ++r)
                Tl[(qh * 16 + lo) * 72 + dt * 16 + hi * 4 + r] = f2bf(o[dt][qh][r] * inv[qh]);
#pragma unroll
    for (int ps = 0; ps < 4; ++ps) {
        int row = ps * 8 + (lane >> 3);
        int col = (lane & 7) * 8;
        bf16x8 v = *(const bf16x8*)&Tl[row * 72 + col];
        *(bf16x8*)&Ob[(size_t)(b * S_ + qr0 + row) * DIM_ + h * 64 + col] = v;
    }
}

// ---------------- launch ----------------
extern "C" void kernel_launch(void* const* d_in, const int* in_sizes, int n_in,
                              void* d_out, int out_size, void* d_ws, size_t ws_size,
                              hipStream_t stream)
{
    const float* x  = (const float*)d_in[0];
    const float* cx = (const float*)d_in[1];
    const void* mask = d_in[2];
    const float* Wq = (const float*)d_in[3];
    const float* bq = (const float*)d_in[4];
    const float* Wk = (const float*)d_in[5];
    const float* bk = (const float*)d_in[6];
    const float* Wv = (const float*)d_in[7];
    const float* bv = (const float*)d_in[8];
    const float* Wo = (const float*)d_in[9];
    const float* bo = (const float*)d_in[10];

    unsigned short* ws = (unsigned short*)d_ws;
    const size_t XB  = 0;                                  // 8192*1024 (x bf16; later attn out)
    const size_t CXB = XB  + (size_t)8192 * 1024;          // 4096*768
    const size_t WQT = CXB + (size_t)4096 * 768;           // 1024*1024
    const size_t WKT = WQT + (size_t)1024 * 1024;          // 1024*768
    const size_t WVT = WKT + (size_t)1024 * 768;           // 1024*768
    const size_t WOT = WVT + (size_t)1024 * 768;           // 1024*1024
    const size_t QB  = WOT + (size_t)1024 * 1024;          // 8192*1024
    const size_t KB  = QB  + (size_t)8192 * 1024;          // 4096*1024
    const size_t VTB = KB  + (size_t)4096 * 1024;          // 4*1024*1024
    const size_t MBT = VTB + (size_t)4 * 1024 * 1024;      // 128 uint32

    k_f32_to_bf16<<<2048, 256, 0, stream>>>(x,  ws + XB,  8192 * 1024 / 4);
    k_f32_to_bf16<<<2048, 256, 0, stream>>>(cx, ws + CXB, 4096 * 768 / 4);
    k_transposeW<<<1024, 256, 0, stream>>>(Wq, ws + WQT, 1024);
    k_transposeW<<<768,  256, 0, stream>>>(Wk, ws + WKT, 768);
    k_transposeW<<<768,  256, 0, stream>>>(Wv, ws + WVT, 768);
    k_transposeW<<<1024, 256, 0, stream>>>(Wo, ws + WOT, 1024);
    unsigned int* mbits = (unsigned int*)(ws + MBT);
    k_mask_bits<<<1, 256, 0, stream>>>((const unsigned int*)mask, mbits);

    dim3 gq(8192 / 128, 1024 / 128);
    dim3 gk(4096 / 128, 1024 / 128);
    k_gemm_bt<0><<<gq, 256, 0, stream>>>(ws + XB,  ws + WQT, bq, ws + QB, nullptr, 8192, 1024, 1024);
    k_gemm_bt<0><<<gk, 256, 0, stream>>>(ws + CXB, ws + WKT, bk, ws + KB, nullptr, 4096, 1024, 768);
    k_gemm_bt<1><<<gk, 256, 0, stream>>>(ws + CXB, ws + WVT, bv, ws + VTB, nullptr, 4096, 1024, 768);

    dim3 ga(S_ / 128, NH_, B_);
    k_attn<<<ga, 256, 0, stream>>>(ws + QB, ws + KB, ws + VTB, mbits, ws + XB);

    k_gemm_bt<2><<<gq, 256, 0, stream>>>(ws + XB, ws + WOT, bo, nullptr, (float*)d_out, 8192, 1024, 1024);
}